// Round 6
// baseline (168.243 us; speedup 1.0000x reference)
//
#include <hip/hip_runtime.h>

#define SCALE_EPS 1e-5f

typedef int v4i __attribute__((ext_vector_type(4)));

static __device__ __forceinline__ void gll16(const void* g, void* l) {
  __builtin_amdgcn_global_load_lds(
      (const __attribute__((address_space(1))) unsigned int*)g,
      (__attribute__((address_space(3))) unsigned int*)l,
      16, 0, 0);
}

// A (activations): signed-i8 fragment-tiled, tile (mt,kc) = 8 KiB at
//   (mt*64+kc)*8192; offset = (row%128/16)*1024 + (k%64/16)*256 + (row%16)*16 + k%16
// B (weights): biased nibble-packed tiles (u = q+8), tile (nt,kc) = 4 KiB at
//   (nt*64+kc)*4096; offset = (f>>1)*1024 + cc*256 + c16*16 + (f&1)*8 + d*4,
//   f=col%128/16, c16=col%16, cc=(k%64)/16, d=(k%16)/8;
//   dword d: byte j = u[k0+8d+j] | (u[k0+8d+j+4]<<4).
// GEMM: A frags direct from LDS; B expanded in-reg (lo=w&0x0f0f0f0f etc).
// Bias removed exactly in epilogue: C = raw - 8*sa[t].

// ---------------------------------------------------------------------------
// Weight unpack: packed int32 [4096][2048] -> biased nibble-packed tiles.
// ---------------------------------------------------------------------------
__global__ __launch_bounds__(256) void unpack_w(const int* __restrict__ wp,
                                                char* __restrict__ wq) {
  const int kc = blockIdx.x;   // 0..63
  const int nt = blockIdx.y;   // 0..31 (128-col units)
  const int tid = threadIdx.x;
  char* tile = wq + ((size_t)nt * 64 + kc) * 4096;
  const int n0 = nt * 128;
#pragma unroll
  for (int gi = 0; gi < 2; ++gi) {
    int g = gi * 256 + tid;        // 0..511: r = g>>2, cc = g&3
    int r = g >> 2, cc = g & 3;
    const v4i* src = (const v4i*)(wp + (size_t)(n0 + r) * 2048 + kc * 32 + cc * 8);
    v4i m0 = src[0], m1 = src[1];  // ints j=0..7 hold k=2j(lo),2j+1(hi)
    unsigned int d0 =
        ((unsigned)m0.x & 15) | (((unsigned)m0.z & 15) << 4) |
        ((((unsigned)m0.x >> 4) & 15) << 8) | ((((unsigned)m0.z >> 4) & 15) << 12) |
        (((unsigned)m0.y & 15) << 16) | (((unsigned)m0.w & 15) << 20) |
        ((((unsigned)m0.y >> 4) & 15) << 24) | ((((unsigned)m0.w >> 4) & 15) << 28);
    unsigned int d1 =
        ((unsigned)m1.x & 15) | (((unsigned)m1.z & 15) << 4) |
        ((((unsigned)m1.x >> 4) & 15) << 8) | ((((unsigned)m1.z >> 4) & 15) << 12) |
        (((unsigned)m1.y & 15) << 16) | (((unsigned)m1.w & 15) << 20) |
        ((((unsigned)m1.y >> 4) & 15) << 24) | ((((unsigned)m1.w >> 4) & 15) << 28);
    d0 ^= 0x88888888u;  // raw nibble v -> v^8 = q+8
    d1 ^= 0x88888888u;
    *(uint2*)(tile + (r >> 5) * 1024 + cc * 256 + (r & 15) * 16 + ((r >> 4) & 1) * 8) =
        make_uint2(d0, d1);
  }
}

// ---------------------------------------------------------------------------
// Activation quant: per-row absmax scale, q = clip(rint(x/scale),-8,7),
// signed-i8 fragment-tiled output + per-token signed sum sa[t].
// ---------------------------------------------------------------------------
__global__ __launch_bounds__(256) void quant_x(const float* __restrict__ x,
                                               char* __restrict__ xq,
                                               float* __restrict__ xs,
                                               int* __restrict__ sa) {
  __shared__ float lmax[4][4];
  __shared__ int lsum[4][4];
  const int tid = threadIdx.x;
  const int w = tid >> 6;        // wave -> k quarter
  const int l = tid & 63;
  const int t0 = blockIdx.x * 4;
  const int row = l >> 4;
  const int t = t0 + row;
  const int sub = l & 15;

  const float* base = x + (size_t)t * 4096 + w * 1024 + sub * 4;
  float4 vals[16];
  float m = 0.0f;
#pragma unroll
  for (int s = 0; s < 16; ++s) {
    vals[s] = *(const float4*)(base + s * 64);
    m = fmaxf(m, fmaxf(fmaxf(fabsf(vals[s].x), fabsf(vals[s].y)),
                       fmaxf(fabsf(vals[s].z), fabsf(vals[s].w))));
  }
#pragma unroll
  for (int d = 1; d < 16; d <<= 1) m = fmaxf(m, __shfl_xor(m, d, 64));
  if (sub == 0) lmax[w][row] = m;
  __syncthreads();
  float rm = fmaxf(fmaxf(lmax[0][row], lmax[1][row]),
                   fmaxf(lmax[2][row], lmax[3][row]));
  float scale = fmaxf(rm / 7.0f, SCALE_EPS);
  if (w == 0 && sub == 0) xs[t] = scale;

  const int mt = t0 >> 7;
  const int f = (t0 & 127) >> 4;
  const int r16 = t & 15;
  const int cc = sub >> 2;
  const int b4 = (sub & 3) * 4;

  int isum = 0;
#pragma unroll
  for (int s = 0; s < 16; ++s) {
    float4 v = vals[s];
    int q0 = (int)fminf(fmaxf(rintf(v.x / scale), -8.0f), 7.0f);
    int q1 = (int)fminf(fmaxf(rintf(v.y / scale), -8.0f), 7.0f);
    int q2 = (int)fminf(fmaxf(rintf(v.z / scale), -8.0f), 7.0f);
    int q3 = (int)fminf(fmaxf(rintf(v.w / scale), -8.0f), 7.0f);
    isum += q0 + q1 + q2 + q3;
    unsigned int wd = (unsigned int)(q0 & 255) | ((unsigned int)(q1 & 255) << 8) |
                      ((unsigned int)(q2 & 255) << 16) | ((unsigned int)(q3 & 255) << 24);
    *(unsigned int*)(xq + ((size_t)mt * 64 + w * 16 + s) * 8192 +
                     f * 1024 + cc * 256 + r16 * 16 + b4) = wd;
  }
#pragma unroll
  for (int dd = 1; dd < 16; dd <<= 1) isum += __shfl_xor(isum, dd, 64);
  if (sub == 0) lsum[w][row] = isum;
  __syncthreads();
  if (w == 0 && sub == 0)
    sa[t] = lsum[0][row] + lsum[1][row] + lsum[2][row] + lsum[3][row];
}

// ---------------------------------------------------------------------------
// Hybrid GEMM, 256x256 tile, 8 waves (2Mx4N), BK=64, mfma_i32_16x16x64_i8.
// A: i8 through LDS (16K/slot), direct MFMA operands, zero expand VALU
//    (A had 4x per-wave unpack redundancy in R4 -> the VALU hotspot).
// B: nibble-packed through LDS (8K/slot), 2 UNPKs/wave/tile (2x redundancy).
// Ring-4 x 24K slots = 96K LDS. 4-phase register rotation, 1 barrier +
// counted vmcnt(3) per tile, setprio around MFMA. Epilogue: C = raw - 8*sa.
// ---------------------------------------------------------------------------
__global__ __launch_bounds__(512, 2) void gemm_i8(const char* __restrict__ xq,
                                                  const char* __restrict__ wq,
                                                  const float* __restrict__ xs,
                                                  const int* __restrict__ sa,
                                                  const float* __restrict__ wsc,
                                                  float* __restrict__ out) {
  __shared__ char lds[4][24576];   // A i8 @0 (16K), B packed @16384 (8K)
  const int tid = threadIdx.x;
  const int wid = tid >> 6;
  const int lane = tid & 63;
  const int wm = wid >> 2;
  const int wn = wid & 3;

  const int bid = blockIdx.x;
  const int wg = (bid & 7) * 64 + (bid >> 3);
  const int by = wg >> 4;          // 0..31
  const int bx = wg & 15;          // 0..15

  const int toff = tid * 16;       // 0..8191
  const char* aSrc0 = xq + (size_t)(2 * by) * 64 * 8192;
  const char* aSrc1 = aSrc0 + 64 * 8192;
  const char* bSrcT = wq + (size_t)(2 * bx + (toff >> 12)) * 262144 + (toff & 4095);
  const int aoff = (lane >> 4) * 256 + (lane & 15) * 16;
  const int laoff = lane * 16;

  v4i acc[8][4] = {};
  v4i fB[2][4];
  v4i aA0, aA1, aA2, aA3;
  v4i pB0, pB1;
  const unsigned MSK = 0x0f0f0f0fu;

#define LO4(w) (int)((unsigned)(w) & MSK)
#define HI4(w) (int)(((unsigned)(w) >> 4) & MSK)
#define UNPK(da, db, p)                                         \
  do {                                                          \
    da = (v4i){LO4((p).x), HI4((p).x), LO4((p).y), HI4((p).y)}; \
    db = (v4i){LO4((p).z), HI4((p).z), LO4((p).w), HI4((p).w)}; \
  } while (0)

#define STAGE3(kt)                                              \
  do {                                                          \
    char* d_ = lds[(kt) & 3];                                   \
    gll16(aSrc0 + (size_t)(kt) * 8192 + toff, d_ + toff);       \
    gll16(aSrc1 + (size_t)(kt) * 8192 + toff, d_ + 8192 + toff);\
    gll16(bSrcT + (size_t)(kt) * 4096, d_ + 16384 + toff);      \
  } while (0)

#define MF2(m0, m1, xx, yy, c)                                                         \
  do {                                                                                 \
    __builtin_amdgcn_s_setprio(1);                                                     \
    _Pragma("unroll") for (int ni = 0; ni < 4; ++ni) {                                 \
      acc[m0][ni] =                                                                    \
          __builtin_amdgcn_mfma_i32_16x16x64_i8(xx, fB[c][ni], acc[m0][ni], 0, 0, 0);  \
      acc[m1][ni] =                                                                    \
          __builtin_amdgcn_mfma_i32_16x16x64_i8(yy, fB[c][ni], acc[m1][ni], 0, 0, 0);  \
    }                                                                                  \
    __builtin_amdgcn_s_setprio(0);                                                     \
  } while (0)

#define TILE(c, kt, do_stage, do_next, vm)                                   \
  do {                                                                       \
    const char* Aw_ = lds[(kt) & 3] + wm * 8192 + laoff;                     \
    const char* Bn_ = lds[((kt) + 1) & 3] + 16384 + wn * 2048 + aoff;        \
    const char* An_ = lds[((kt) + 1) & 3] + wm * 8192 + laoff;               \
    /* P0: read A frags 2,3 ; MFMA frags 0,1 */                              \
    aA2 = *(const v4i*)(Aw_ + 2048);                                         \
    aA3 = *(const v4i*)(Aw_ + 3072);                                         \
    MF2(0, 1, aA0, aA1, c);                                                  \
    /* P1: read A frags 4,5 ; MFMA frags 2,3 */                              \
    aA0 = *(const v4i*)(Aw_ + 4096);                                         \
    aA1 = *(const v4i*)(Aw_ + 5120);                                         \
    MF2(2, 3, aA2, aA3, c);                                                  \
    /* mid-tile: certify slot kt+1 (counted), sync */                        \
    if ((vm) == 3) asm volatile("s_waitcnt vmcnt(3)" ::: "memory");          \
    else if ((vm) == 0) asm volatile("s_waitcnt vmcnt(0)" ::: "memory");     \
    __builtin_amdgcn_s_barrier();                                            \
    __builtin_amdgcn_sched_barrier(0);                                       \
    /* P2: stage kt+3; read A frags 6,7 + next-B pair0; MFMA frags 4,5 */    \
    if (do_stage) STAGE3((kt) + 3);                                          \
    aA2 = *(const v4i*)(Aw_ + 6144);                                         \
    aA3 = *(const v4i*)(Aw_ + 7168);                                         \
    if (do_next) pB0 = *(const v4i*)(Bn_);                                   \
    MF2(4, 5, aA0, aA1, c);                                                  \
    /* P3: read next-B pair1 + next-A frags 0,1; MFMA frags 6,7; unpack B */ \
    if (do_next) {                                                           \
      pB1 = *(const v4i*)(Bn_ + 1024);                                       \
      aA0 = *(const v4i*)(An_);                                              \
      aA1 = *(const v4i*)(An_ + 1024);                                       \
    }                                                                        \
    MF2(6, 7, aA2, aA3, c);                                                  \
    if (do_next) {                                                           \
      UNPK(fB[1 - (c)][0], fB[1 - (c)][1], pB0);                             \
      UNPK(fB[1 - (c)][2], fB[1 - (c)][3], pB1);                             \
    }                                                                        \
  } while (0)

  // prologue: stage 0,1,2 (9 loads); certify slot 0; preload B(0) + A 0,1
  STAGE3(0); STAGE3(1); STAGE3(2);
  asm volatile("s_waitcnt vmcnt(6)" ::: "memory");
  __builtin_amdgcn_s_barrier();
  __builtin_amdgcn_sched_barrier(0);
  {
    const char* B0_ = lds[0] + 16384 + wn * 2048 + aoff;
    pB0 = *(const v4i*)(B0_);
    pB1 = *(const v4i*)(B0_ + 1024);
    aA0 = *(const v4i*)(lds[0] + wm * 8192 + laoff);
    aA1 = *(const v4i*)(lds[0] + wm * 8192 + laoff + 1024);
    UNPK(fB[0][0], fB[0][1], pB0);
    UNPK(fB[0][2], fB[0][3], pB1);
  }

  for (int kt = 0; kt < 60; kt += 2) {
    TILE(0, kt, 1, 1, 3);
    TILE(1, kt + 1, 1, 1, 3);
  }
  TILE(0, 60, 1, 1, 3);   // stages slot 63 (last)
  TILE(1, 61, 0, 1, 3);   // slot 62 certified (63's 3 loads remain)
  TILE(0, 62, 0, 1, 0);   // slot 63 certified
  TILE(1, 63, 0, 0, -1);  // pure drain

#undef TILE
#undef MF2
#undef STAGE3
#undef UNPK
#undef LO4
#undef HI4

  // epilogue: D row = (lane>>4)*4 + j, col = lane&15; C = raw - 8*sa[t]
  float wvv[4];
#pragma unroll
  for (int ni = 0; ni < 4; ++ni)
    wvv[ni] = wsc[bx * 256 + wn * 64 + ni * 16 + (lane & 15)];
  const int rbase = by * 256 + wm * 128 + ((lane >> 4) << 2);
  const int cbase = bx * 256 + wn * 64 + (lane & 15);
#pragma unroll
  for (int mi = 0; mi < 8; ++mi) {
#pragma unroll
    for (int j = 0; j < 4; ++j) {
      int t = rbase + mi * 16 + j;
      int sat = sa[t];
      float xsv = xs[t];
      float* orow = out + (size_t)t * 4096 + cbase;
#pragma unroll
      for (int ni = 0; ni < 4; ++ni) {
        int cv = acc[mi][ni][j] - 8 * sat;
        orow[ni * 16] = (float)cv * (xsv * wvv[ni]);
      }
    }
  }
}

extern "C" void kernel_launch(void* const* d_in, const int* in_sizes, int n_in,
                              void* d_out, int out_size, void* d_ws, size_t ws_size,
                              hipStream_t stream) {
  const float* x = (const float*)d_in[0];
  const int* wp = (const int*)d_in[1];
  const float* wsc = (const float*)d_in[2];
  float* out = (float*)d_out;
  char* ws = (char*)d_ws;

  char* xq = ws;                                   // 8192*4096 i8 = 33554432 B
  char* wq = ws + 33554432;                        // packed 4096*2048 = 8388608 B
  float* xs = (float*)(ws + 41943040);             // 8192*4
  int* sa = (int*)(ws + 41943040 + 32768);         // 8192*4

  hipLaunchKernelGGL(unpack_w, dim3(64, 32), dim3(256), 0, stream, wp, wq);
  hipLaunchKernelGGL(quant_x, dim3(2048), dim3(256), 0, stream, x, xq, xs, sa);
  hipLaunchKernelGGL(gemm_i8, dim3(512), dim3(512), 0, stream, xq, wq, xs, sa, wsc, out);
}